// Round 1
// baseline (785.763 us; speedup 1.0000x reference)
//
#include <hip/hip_runtime.h>

#define BB 2
#define HH 256
#define WW 256
#define ZZ 256
#define NROWS (BB * HH * WW)            // 131072
#define NELEM ((long long)NROWS * ZZ)   // 33554432

// d_ws layout: [0..7] double loss accumulator, [8..11] uint absmax accumulator
__global__ __launch_bounds__(256) void stencil7_kernel(
    const float* __restrict__ x, const float* __restrict__ coeff,
    const float* __restrict__ ref, float* __restrict__ out,
    double* __restrict__ loss_acc, unsigned int* __restrict__ amax_acc)
{
    const int tid  = threadIdx.x;
    const int wave = tid >> 6;
    const int lane = tid & 63;
    const int r    = blockIdx.x * 4 + wave;          // row index in [0, NROWS)
    const int w    = r & (WW - 1);
    const int h    = (r >> 8) & (HH - 1);
    const long long base = (long long)r * ZZ;
    const int z0   = lane << 2;

    const float4 cen = *(const float4*)(x + base + z0);
    float4 west  = make_float4(0.f, 0.f, 0.f, 0.f);
    float4 east  = west, south = west, north = west;
    if (w > 0)      west  = *(const float4*)(x + base - ZZ + z0);
    if (w < WW - 1) east  = *(const float4*)(x + base + ZZ + z0);
    if (h > 0)      south = *(const float4*)(x + base - (long long)WW * ZZ + z0);
    if (h < HH - 1) north = *(const float4*)(x + base + (long long)WW * ZZ + z0);
    const float4 rf = *(const float4*)(ref + base + z0);

    const float* cp = coeff + (long long)r * 7;
    const float c0 = cp[0], c1 = cp[1], c2 = cp[2], c3 = cp[3];
    const float c4 = cp[4], c5 = cp[5], c6 = cp[6];

    // Z-direction shifts via cross-lane shuffle (wave = one full row)
    float bm1 = __shfl_up(cen.w, 1);
    if (lane == 0) bm1 = 0.f;           // z=0: bottom is zero
    float tp1 = __shfl_down(cen.x, 1);
    if (lane == 63) tp1 = 0.f;          // z=255: top is zero

    const float4 bot = make_float4(bm1, cen.x, cen.y, cen.z);
    const float4 top = make_float4(cen.y, cen.z, cen.w, tp1);

    float4 o;
    o.x = c0*west.x + c1*east.x + c2*south.x + c3*north.x + c4*bot.x + c5*top.x + c6*cen.x;
    o.y = c0*west.y + c1*east.y + c2*south.y + c3*north.y + c4*bot.y + c5*top.y + c6*cen.y;
    o.z = c0*west.z + c1*east.z + c2*south.z + c3*north.z + c4*bot.z + c5*top.z + c6*cen.z;
    o.w = c0*west.w + c1*east.w + c2*south.w + c3*north.w + c4*bot.w + c5*top.w + c6*cen.w;

    // store (out is d_out+1, only 4B aligned -> scalar dword stores)
    float* op = out + base + z0;
    op[0] = o.x; op[1] = o.y; op[2] = o.z; op[3] = o.w;

    // error reductions
    const float ex = o.x - rf.x, ey = o.y - rf.y, ez = o.z - rf.z, ew = o.w - rf.w;
    float s = ex*ex + ey*ey + ez*ez + ew*ew;
    float m = fmaxf(fmaxf(fabsf(ex), fabsf(ey)), fmaxf(fabsf(ez), fabsf(ew)));

    #pragma unroll
    for (int off = 32; off > 0; off >>= 1) {
        s += __shfl_down(s, off);
        m  = fmaxf(m, __shfl_down(m, off));
    }

    __shared__ float ss[4];
    __shared__ float sm[4];
    if (lane == 0) { ss[wave] = s; sm[wave] = m; }
    __syncthreads();
    if (tid == 0) {
        const float S = ss[0] + ss[1] + ss[2] + ss[3];
        const float M = fmaxf(fmaxf(sm[0], sm[1]), fmaxf(sm[2], sm[3]));
        atomicAdd(loss_acc, (double)S);
        atomicMax(amax_acc, __float_as_uint(M));  // valid: all values >= 0
    }
}

__global__ void finalize_kernel(const double* __restrict__ loss_acc,
                                const unsigned int* __restrict__ amax_acc,
                                float* __restrict__ loss_out,
                                float* __restrict__ amax_out)
{
    *loss_out = (float)(*loss_acc / (double)NELEM);
    *amax_out = __uint_as_float(*amax_acc);
}

extern "C" void kernel_launch(void* const* d_in, const int* in_sizes, int n_in,
                              void* d_out, int out_size, void* d_ws, size_t ws_size,
                              hipStream_t stream) {
    const float* x     = (const float*)d_in[0];
    const float* coeff = (const float*)d_in[1];
    const float* ref   = (const float*)d_in[2];

    float* outf = (float*)d_out;
    float* loss_out = outf;               // d_out[0]
    float* out_body = outf + 1;           // d_out[1 .. N]
    float* amax_out = outf + 1 + NELEM;   // d_out[N+1]

    double* loss_acc = (double*)d_ws;
    unsigned int* amax_acc = (unsigned int*)((char*)d_ws + 8);

    hipMemsetAsync(d_ws, 0, 16, stream);

    dim3 grid(NROWS / 4);
    dim3 block(256);
    stencil7_kernel<<<grid, block, 0, stream>>>(x, coeff, ref, out_body,
                                                loss_acc, amax_acc);
    finalize_kernel<<<1, 1, 0, stream>>>(loss_acc, amax_acc, loss_out, amax_out);
}

// Round 2
// 99.780 us; speedup vs baseline: 7.8750x; 7.8750x over previous
//
#include <hip/hip_runtime.h>

#define BB 2
#define HH 256
#define WW 256
#define ZZ 256
#define NROWS (BB * HH * WW)            // 131072
#define NELEM ((long long)NROWS * ZZ)   // 33554432

#define NBLK 2048
#define WPB 4                            // waves per block
#define TOT_WAVES (NBLK * WPB)           // 8192
#define ROWS_PER_WAVE (NROWS / TOT_WAVES) // 16

// d_ws layout: float part_sum[NBLK]; float part_max[NBLK]   (16 KB)
__global__ __launch_bounds__(256) void stencil7_kernel(
    const float* __restrict__ x, const float* __restrict__ coeff,
    const float* __restrict__ ref, float* __restrict__ out,
    float* __restrict__ part_sum, float* __restrict__ part_max)
{
    const int tid  = threadIdx.x;
    const int wave = tid >> 6;
    const int lane = tid & 63;
    const int waveId = blockIdx.x * WPB + wave;
    const int z0   = lane << 2;

    float acc_s = 0.f;
    float acc_m = 0.f;

    #pragma unroll 1
    for (int it = 0; it < ROWS_PER_WAVE; ++it) {
        const int r = waveId + it * TOT_WAVES;   // row index
        const int w = r & (WW - 1);
        const int h = (r >> 8) & (HH - 1);
        const long long base = (long long)r * ZZ;

        const float4 cen = *(const float4*)(x + base + z0);
        float4 west  = make_float4(0.f, 0.f, 0.f, 0.f);
        float4 east  = west, south = west, north = west;
        if (w > 0)      west  = *(const float4*)(x + base - ZZ + z0);
        if (w < WW - 1) east  = *(const float4*)(x + base + ZZ + z0);
        if (h > 0)      south = *(const float4*)(x + base - (long long)WW * ZZ + z0);
        if (h < HH - 1) north = *(const float4*)(x + base + (long long)WW * ZZ + z0);
        const float4 rf = *(const float4*)(ref + base + z0);

        const float* cp = coeff + (long long)r * 7;
        const float c0 = cp[0], c1 = cp[1], c2 = cp[2], c3 = cp[3];
        const float c4 = cp[4], c5 = cp[5], c6 = cp[6];

        // Z-direction shifts via cross-lane shuffle (wave = one full Z-row)
        float bm1 = __shfl_up(cen.w, 1);
        if (lane == 0) bm1 = 0.f;
        float tp1 = __shfl_down(cen.x, 1);
        if (lane == 63) tp1 = 0.f;

        const float4 bot = make_float4(bm1, cen.x, cen.y, cen.z);
        const float4 top = make_float4(cen.y, cen.z, cen.w, tp1);

        float4 o;
        o.x = c0*west.x + c1*east.x + c2*south.x + c3*north.x + c4*bot.x + c5*top.x + c6*cen.x;
        o.y = c0*west.y + c1*east.y + c2*south.y + c3*north.y + c4*bot.y + c5*top.y + c6*cen.y;
        o.z = c0*west.z + c1*east.z + c2*south.z + c3*north.z + c4*bot.z + c5*top.z + c6*cen.z;
        o.w = c0*west.w + c1*east.w + c2*south.w + c3*north.w + c4*bot.w + c5*top.w + c6*cen.w;

        float* op = out + base + z0;   // out = d_out+1, 4B-aligned only
        op[0] = o.x; op[1] = o.y; op[2] = o.z; op[3] = o.w;

        const float ex = o.x - rf.x, ey = o.y - rf.y, ez = o.z - rf.z, ew = o.w - rf.w;
        acc_s += ex*ex + ey*ey + ez*ez + ew*ew;
        acc_m  = fmaxf(acc_m, fmaxf(fmaxf(fabsf(ex), fabsf(ey)),
                                    fmaxf(fabsf(ez), fabsf(ew))));
    }

    // wave reduction
    #pragma unroll
    for (int off = 32; off > 0; off >>= 1) {
        acc_s += __shfl_down(acc_s, off);
        acc_m  = fmaxf(acc_m, __shfl_down(acc_m, off));
    }

    __shared__ float ss[WPB];
    __shared__ float sm[WPB];
    if (lane == 0) { ss[wave] = acc_s; sm[wave] = acc_m; }
    __syncthreads();
    if (tid == 0) {
        part_sum[blockIdx.x] = ss[0] + ss[1] + ss[2] + ss[3];
        part_max[blockIdx.x] = fmaxf(fmaxf(sm[0], sm[1]), fmaxf(sm[2], sm[3]));
    }
}

__global__ __launch_bounds__(256) void finalize_kernel(
    const float* __restrict__ part_sum, const float* __restrict__ part_max,
    float* __restrict__ loss_out, float* __restrict__ amax_out)
{
    const int tid  = threadIdx.x;
    const int wave = tid >> 6;
    const int lane = tid & 63;

    double s = 0.0;
    float  m = 0.f;
    for (int i = tid; i < NBLK; i += 256) {
        s += (double)part_sum[i];
        m  = fmaxf(m, part_max[i]);
    }
    #pragma unroll
    for (int off = 32; off > 0; off >>= 1) {
        s += __shfl_down(s, off);
        m  = fmaxf(m, __shfl_down(m, off));
    }
    __shared__ double ds[4];
    __shared__ float  dm[4];
    if (lane == 0) { ds[wave] = s; dm[wave] = m; }
    __syncthreads();
    if (tid == 0) {
        const double S = ds[0] + ds[1] + ds[2] + ds[3];
        const float  M = fmaxf(fmaxf(dm[0], dm[1]), fmaxf(dm[2], dm[3]));
        *loss_out = (float)(S / (double)NELEM);
        *amax_out = M;
    }
}

extern "C" void kernel_launch(void* const* d_in, const int* in_sizes, int n_in,
                              void* d_out, int out_size, void* d_ws, size_t ws_size,
                              hipStream_t stream) {
    const float* x     = (const float*)d_in[0];
    const float* coeff = (const float*)d_in[1];
    const float* ref   = (const float*)d_in[2];

    float* outf = (float*)d_out;
    float* loss_out = outf;               // d_out[0]
    float* out_body = outf + 1;           // d_out[1 .. N]
    float* amax_out = outf + 1 + NELEM;   // d_out[N+1]

    float* part_sum = (float*)d_ws;
    float* part_max = part_sum + NBLK;

    stencil7_kernel<<<dim3(NBLK), dim3(256), 0, stream>>>(
        x, coeff, ref, out_body, part_sum, part_max);
    finalize_kernel<<<dim3(1), dim3(256), 0, stream>>>(
        part_sum, part_max, loss_out, amax_out);
}

// Round 3
// 95.925 us; speedup vs baseline: 8.1915x; 1.0402x over previous
//
#include <hip/hip_runtime.h>

#define BB 2
#define HH 256
#define WW 256
#define ZZ 256
#define NROWS (BB * HH * WW)            // 131072
#define NELEM ((long long)NROWS * ZZ)   // 33554432

#define NBLK 2048
#define WPB 4
#define NSEG (NBLK * WPB)               // 8192 waves
#define SEGROWS (NROWS / NSEG)          // 16 consecutive rows per wave

__device__ __forceinline__ float4 ld4(const float* p) { return *(const float4*)p; }

// d_ws layout: float part_sum[NBLK]; float part_max[NBLK]
__global__ __launch_bounds__(256) void stencil7_kernel(
    const float* __restrict__ x, const float* __restrict__ coeff,
    const float* __restrict__ ref, float* __restrict__ out,
    float* __restrict__ part_sum, float* __restrict__ part_max)
{
    const int tid  = threadIdx.x;
    const int wave = tid >> 6;
    const int lane = tid & 63;
    const int seg  = blockIdx.x * WPB + wave;     // 0..NSEG-1
    const int r0   = seg * SEGROWS;               // first row of segment
    const int w0   = r0 & (WW - 1);               // w of first row (multiple of 16)
    const int h    = (r0 >> 8) & (HH - 1);        // constant across segment
    const long long b0 = (long long)r0 * ZZ + (lane << 2);

    const bool hasS = (h > 0);
    const bool hasN = (h < HH - 1);
    const float4 z4 = make_float4(0.f, 0.f, 0.f, 0.f);

    const float* px  = x + b0;
    const float* prf = ref + b0;
    const float* pcf = coeff + (long long)r0 * 7;
    float* po = out + b0;

    const long long SO = -(long long)WW * ZZ;     // south offset
    const long long NO =  (long long)WW * ZZ;     // north offset

    // ---- prologue: row 0 state + center ring depth 2 ----
    float4 c_m1 = (w0 > 0) ? ld4(px - ZZ) : z4;   // west of row 0
    float4 c_0  = ld4(px);                        // center row 0
    float4 c_1  = ld4(px + ZZ);                   // center row 1 (always in-segment)
    float4 s_c  = hasS ? ld4(px + SO) : z4;
    float4 n_c  = hasN ? ld4(px + NO) : z4;
    float4 rf_c = ld4(prf);
    float cc0 = pcf[0], cc1 = pcf[1], cc2 = pcf[2], cc3 = pcf[3],
          cc4 = pcf[4], cc5 = pcf[5], cc6 = pcf[6];

    float acc_s = 0.f, acc_m = 0.f;

    #pragma unroll 4
    for (int i = 0; i < SEGROWS; ++i) {
        // prefetch center of row i+2 (becomes east of row i+1)
        float4 c_2 = z4;
        if (i + 2 < SEGROWS) {
            c_2 = ld4(px + (long long)(i + 2) * ZZ);
        } else if (i + 2 == SEGROWS) {
            if ((w0 + SEGROWS) < WW) c_2 = ld4(px + (long long)SEGROWS * ZZ);
        }
        // prefetch row i+1 extras
        float4 s_n = z4, n_n = z4, rf_n = z4;
        float cn0 = 0.f, cn1 = 0.f, cn2 = 0.f, cn3 = 0.f, cn4 = 0.f, cn5 = 0.f, cn6 = 0.f;
        if (i + 1 < SEGROWS) {
            const long long ro = (long long)(i + 1) * ZZ;
            if (hasS) s_n = ld4(px + ro + SO);
            if (hasN) n_n = ld4(px + ro + NO);
            rf_n = ld4(prf + ro);
            const float* cnp = pcf + (i + 1) * 7;
            cn0 = cnp[0]; cn1 = cnp[1]; cn2 = cnp[2]; cn3 = cnp[3];
            cn4 = cnp[4]; cn5 = cnp[5]; cn6 = cnp[6];
        }

        // ---- compute row i: west=c_m1, center=c_0, east=c_1 ----
        float bm1 = __shfl_up(c_0.w, 1);
        if (lane == 0) bm1 = 0.f;
        float tp1 = __shfl_down(c_0.x, 1);
        if (lane == 63) tp1 = 0.f;
        const float4 bot = make_float4(bm1, c_0.x, c_0.y, c_0.z);
        const float4 top = make_float4(c_0.y, c_0.z, c_0.w, tp1);

        float4 o;
        o.x = cc0*c_m1.x + cc1*c_1.x + cc2*s_c.x + cc3*n_c.x + cc4*bot.x + cc5*top.x + cc6*c_0.x;
        o.y = cc0*c_m1.y + cc1*c_1.y + cc2*s_c.y + cc3*n_c.y + cc4*bot.y + cc5*top.y + cc6*c_0.y;
        o.z = cc0*c_m1.z + cc1*c_1.z + cc2*s_c.z + cc3*n_c.z + cc4*bot.z + cc5*top.z + cc6*c_0.z;
        o.w = cc0*c_m1.w + cc1*c_1.w + cc2*s_c.w + cc3*n_c.w + cc4*bot.w + cc5*top.w + cc6*c_0.w;

        float* op = po + (long long)i * ZZ;       // 4B-aligned only (out = d_out+1)
        op[0] = o.x; op[1] = o.y; op[2] = o.z; op[3] = o.w;

        const float ex = o.x - rf_c.x, ey = o.y - rf_c.y,
                    ez = o.z - rf_c.z, ew = o.w - rf_c.w;
        acc_s += ex*ex + ey*ey + ez*ez + ew*ew;
        acc_m  = fmaxf(acc_m, fmaxf(fmaxf(fabsf(ex), fabsf(ey)),
                                    fmaxf(fabsf(ez), fabsf(ew))));

        // rotate pipeline
        c_m1 = c_0; c_0 = c_1; c_1 = c_2;
        s_c = s_n; n_c = n_n; rf_c = rf_n;
        cc0 = cn0; cc1 = cn1; cc2 = cn2; cc3 = cn3; cc4 = cn4; cc5 = cn5; cc6 = cn6;
    }

    // wave reduction
    #pragma unroll
    for (int off = 32; off > 0; off >>= 1) {
        acc_s += __shfl_down(acc_s, off);
        acc_m  = fmaxf(acc_m, __shfl_down(acc_m, off));
    }

    __shared__ float ss[WPB];
    __shared__ float sm[WPB];
    if (lane == 0) { ss[wave] = acc_s; sm[wave] = acc_m; }
    __syncthreads();
    if (tid == 0) {
        part_sum[blockIdx.x] = ss[0] + ss[1] + ss[2] + ss[3];
        part_max[blockIdx.x] = fmaxf(fmaxf(sm[0], sm[1]), fmaxf(sm[2], sm[3]));
    }
}

__global__ __launch_bounds__(256) void finalize_kernel(
    const float* __restrict__ part_sum, const float* __restrict__ part_max,
    float* __restrict__ loss_out, float* __restrict__ amax_out)
{
    const int tid  = threadIdx.x;
    const int wave = tid >> 6;
    const int lane = tid & 63;

    double s = 0.0;
    float  m = 0.f;
    for (int i = tid; i < NBLK; i += 256) {
        s += (double)part_sum[i];
        m  = fmaxf(m, part_max[i]);
    }
    #pragma unroll
    for (int off = 32; off > 0; off >>= 1) {
        s += __shfl_down(s, off);
        m  = fmaxf(m, __shfl_down(m, off));
    }
    __shared__ double ds[4];
    __shared__ float  dm[4];
    if (lane == 0) { ds[wave] = s; dm[wave] = m; }
    __syncthreads();
    if (tid == 0) {
        const double S = ds[0] + ds[1] + ds[2] + ds[3];
        const float  M = fmaxf(fmaxf(dm[0], dm[1]), fmaxf(dm[2], dm[3]));
        *loss_out = (float)(S / (double)NELEM);
        *amax_out = M;
    }
}

extern "C" void kernel_launch(void* const* d_in, const int* in_sizes, int n_in,
                              void* d_out, int out_size, void* d_ws, size_t ws_size,
                              hipStream_t stream) {
    const float* x     = (const float*)d_in[0];
    const float* coeff = (const float*)d_in[1];
    const float* ref   = (const float*)d_in[2];

    float* outf = (float*)d_out;
    float* loss_out = outf;               // d_out[0]
    float* out_body = outf + 1;           // d_out[1 .. N]
    float* amax_out = outf + 1 + NELEM;   // d_out[N+1]

    float* part_sum = (float*)d_ws;
    float* part_max = part_sum + NBLK;

    stencil7_kernel<<<dim3(NBLK), dim3(256), 0, stream>>>(
        x, coeff, ref, out_body, part_sum, part_max);
    finalize_kernel<<<dim3(1), dim3(256), 0, stream>>>(
        part_sum, part_max, loss_out, amax_out);
}

// Round 4
// 95.076 us; speedup vs baseline: 8.2646x; 1.0089x over previous
//
#include <hip/hip_runtime.h>

#define BB 2
#define HH 256
#define WW 256
#define ZZ 256
#define NROWS (BB * HH * WW)            // 131072
#define NELEM ((long long)NROWS * ZZ)   // 33554432

#define TW 16                            // w-steps per tile
#define NTW (WW / TW)                    // 16 w-tiles
#define NQ (BB * HH / 4)                 // 128 h-quads
#define NBLK (NQ * NTW)                  // 2048 blocks

__device__ __forceinline__ float4 ld4(const float* p) { return *(const float4*)p; }

__device__ __forceinline__ void stage_row(const float* src, void* ldsdst) {
    // async global->LDS, 16B/lane; LDS dest = uniform base + lane*16 (linear)
    __builtin_amdgcn_global_load_lds(
        (const __attribute__((address_space(1))) void*)src,
        (__attribute__((address_space(3))) void*)ldsdst, 16, 0, 0);
}

// d_ws layout: float part_sum[NBLK]; float part_max[NBLK]
__global__ __launch_bounds__(256, 4) void stencil7_kernel(
    const float* __restrict__ x, const float* __restrict__ coeff,
    const float* __restrict__ ref, float* __restrict__ out,
    float* __restrict__ part_sum, float* __restrict__ part_max)
{
    __shared__ float lds[4][4][ZZ];      // [ring slot][wave row][z]  16 KB
    __shared__ float ss[4], sm[4];

    const int tid  = threadIdx.x;
    const int k    = tid >> 6;           // wave index = row within quad
    const int lane = tid & 63;
    const int qt   = blockIdx.x / NTW;   // h-quad id
    const int wt   = blockIdx.x % NTW;   // w-tile id
    const int w0   = wt * TW;
    const int bh   = qt * 4 + k;         // combined b*HH+h row, wave-uniform
    const int h    = bh & (HH - 1);
    const bool has_s = (h > 0);          // only relevant for k==0
    const bool has_n = (h < HH - 1);     // only relevant for k==3
    const float4 z4 = make_float4(0.f, 0.f, 0.f, 0.f);

    const int lo = lane << 2;            // float offset within row

    // ---- prologue: stage w0-1, w0, w0+1 into ring slots 3,0,1 ----
    {
        const int wm = (w0 > 0) ? w0 - 1 : 0;   // clamped; selected away at w==0
        stage_row(x + (long long)(bh * WW + wm) * ZZ + lo, &lds[3][k][0]);
        stage_row(x + (long long)(bh * WW + w0) * ZZ + lo, &lds[0][k][0]);
        stage_row(x + (long long)(bh * WW + w0 + 1) * ZZ + lo, &lds[1][k][0]);
    }
    // prologue register prefetch for step 0
    float4 rf_c = ld4(ref + (long long)(bh * WW + w0) * ZZ + lo);
    float4 sg_c = z4, ng_c = z4;
    if (k == 0 && has_s) sg_c = ld4(x + (long long)((bh - 1) * WW + w0) * ZZ + lo);
    if (k == 3 && has_n) ng_c = ld4(x + (long long)((bh + 1) * WW + w0) * ZZ + lo);
    // coeff for step 0 via scalar path (uniform address)
    const float* cp0 = coeff + (long long)__builtin_amdgcn_readfirstlane(bh * WW + w0) * 7;
    float c0 = cp0[0], c1 = cp0[1], c2 = cp0[2], c3 = cp0[3],
          c4 = cp0[4], c5 = cp0[5], c6 = cp0[6];

    __syncthreads();                     // stages for slots 3,0,1 complete

    float4 cw = *(const float4*)&lds[3][k][lo];   // west of step 0 (maybe fake)
    float4 cc = *(const float4*)&lds[0][k][lo];   // center of step 0

    float acc_s = 0.f, acc_m = 0.f;

    const int ks = (k == 0) ? 0 : k - 1;  // clamped neighbor indices (in-bounds)
    const int kn = (k == 3) ? 3 : k + 1;

    #pragma unroll
    for (int i = 0; i < TW; ++i) {
        const int w = w0 + i;

        // issue stage for step i+1's east: row w+2, slot (i+2)&3 (clamped)
        {
            int wsd = w + 2; if (wsd > WW - 1) wsd = WW - 1;
            stage_row(x + (long long)(bh * WW + wsd) * ZZ + lo, &lds[(i + 2) & 3][k][0]);
        }
        // register prefetch for step i+1 (clamped w+1; dead at i==15)
        int wn = w + 1; if (wn > WW - 1) wn = WW - 1;
        float4 rf_n = ld4(ref + (long long)(bh * WW + wn) * ZZ + lo);
        float4 sg_n = z4, ng_n = z4;
        if (k == 0 && has_s) sg_n = ld4(x + (long long)((bh - 1) * WW + wn) * ZZ + lo);
        if (k == 3 && has_n) ng_n = ld4(x + (long long)((bh + 1) * WW + wn) * ZZ + lo);
        const float* cpn = coeff + (long long)__builtin_amdgcn_readfirstlane(bh * WW + wn) * 7;
        const float d0 = cpn[0], d1 = cpn[1], d2 = cpn[2], d3 = cpn[3],
                    d4 = cpn[4], d5 = cpn[5], d6 = cpn[6];

        // LDS reads for this step
        float4 ce  = *(const float4*)&lds[(i + 1) & 3][k][lo];
        float4 svd = *(const float4*)&lds[i & 3][ks][lo];
        float4 nvd = *(const float4*)&lds[i & 3][kn][lo];
        const float4 sv = (k == 0) ? sg_c : svd;   // sg_c is z4 when !has_s
        const float4 nv = (k == 3) ? ng_c : nvd;
        const float4 wv = (w == 0)      ? z4 : cw;
        const float4 ev = (w == WW - 1) ? z4 : ce;

        // Z shifts on center (wave = one full Z-row)
        float bm1 = __shfl_up(cc.w, 1);
        if (lane == 0) bm1 = 0.f;
        float tp1 = __shfl_down(cc.x, 1);
        if (lane == 63) tp1 = 0.f;
        const float4 bot = make_float4(bm1, cc.x, cc.y, cc.z);
        const float4 top = make_float4(cc.y, cc.z, cc.w, tp1);

        float4 o;
        o.x = c0*wv.x + c1*ev.x + c2*sv.x + c3*nv.x + c4*bot.x + c5*top.x + c6*cc.x;
        o.y = c0*wv.y + c1*ev.y + c2*sv.y + c3*nv.y + c4*bot.y + c5*top.y + c6*cc.y;
        o.z = c0*wv.z + c1*ev.z + c2*sv.z + c3*nv.z + c4*bot.z + c5*top.z + c6*cc.z;
        o.w = c0*wv.w + c1*ev.w + c2*sv.w + c3*nv.w + c4*bot.w + c5*top.w + c6*cc.w;

        float* op = out + (long long)(bh * WW + w) * ZZ + lo;  // 4B-aligned
        op[0] = o.x; op[1] = o.y; op[2] = o.z; op[3] = o.w;

        const float ex = o.x - rf_c.x, ey = o.y - rf_c.y,
                    ez = o.z - rf_c.z, ew = o.w - rf_c.w;
        acc_s += ex*ex + ey*ey + ez*ez + ew*ew;
        acc_m  = fmaxf(acc_m, fmaxf(fmaxf(fabsf(ex), fabsf(ey)),
                                    fmaxf(fabsf(ez), fabsf(ew))));

        // rotate pipeline state
        cw = cc; cc = ce;
        rf_c = rf_n; sg_c = sg_n; ng_c = ng_n;
        c0 = d0; c1 = d1; c2 = d2; c3 = d3; c4 = d4; c5 = d5; c6 = d6;

        __syncthreads();   // drains this step's stage + prefetches; publishes LDS
    }

    // wave reduction
    #pragma unroll
    for (int off = 32; off > 0; off >>= 1) {
        acc_s += __shfl_down(acc_s, off);
        acc_m  = fmaxf(acc_m, __shfl_down(acc_m, off));
    }
    if (lane == 0) { ss[k] = acc_s; sm[k] = acc_m; }
    __syncthreads();
    if (tid == 0) {
        part_sum[blockIdx.x] = ss[0] + ss[1] + ss[2] + ss[3];
        part_max[blockIdx.x] = fmaxf(fmaxf(sm[0], sm[1]), fmaxf(sm[2], sm[3]));
    }
}

__global__ __launch_bounds__(256) void finalize_kernel(
    const float* __restrict__ part_sum, const float* __restrict__ part_max,
    float* __restrict__ loss_out, float* __restrict__ amax_out)
{
    const int tid  = threadIdx.x;
    const int wave = tid >> 6;
    const int lane = tid & 63;

    double s = 0.0;
    float  m = 0.f;
    for (int i = tid; i < NBLK; i += 256) {
        s += (double)part_sum[i];
        m  = fmaxf(m, part_max[i]);
    }
    #pragma unroll
    for (int off = 32; off > 0; off >>= 1) {
        s += __shfl_down(s, off);
        m  = fmaxf(m, __shfl_down(m, off));
    }
    __shared__ double ds[4];
    __shared__ float  dm[4];
    if (lane == 0) { ds[wave] = s; dm[wave] = m; }
    __syncthreads();
    if (tid == 0) {
        const double S = ds[0] + ds[1] + ds[2] + ds[3];
        const float  M = fmaxf(fmaxf(dm[0], dm[1]), fmaxf(dm[2], dm[3]));
        *loss_out = (float)(S / (double)NELEM);
        *amax_out = M;
    }
}

extern "C" void kernel_launch(void* const* d_in, const int* in_sizes, int n_in,
                              void* d_out, int out_size, void* d_ws, size_t ws_size,
                              hipStream_t stream) {
    const float* x     = (const float*)d_in[0];
    const float* coeff = (const float*)d_in[1];
    const float* ref   = (const float*)d_in[2];

    float* outf = (float*)d_out;
    float* loss_out = outf;               // d_out[0]
    float* out_body = outf + 1;           // d_out[1 .. N]
    float* amax_out = outf + 1 + NELEM;   // d_out[N+1]

    float* part_sum = (float*)d_ws;
    float* part_max = part_sum + NBLK;

    stencil7_kernel<<<dim3(NBLK), dim3(256), 0, stream>>>(
        x, coeff, ref, out_body, part_sum, part_max);
    finalize_kernel<<<dim3(1), dim3(256), 0, stream>>>(
        part_sum, part_max, loss_out, amax_out);
}

// Round 6
// 92.262 us; speedup vs baseline: 8.5166x; 1.0305x over previous
//
#include <hip/hip_runtime.h>

#define BB 2
#define HH 256
#define WW 256
#define ZZ 256
#define NROWS (BB * HH * WW)            // 131072
#define NELEM ((long long)NROWS * ZZ)   // 33554432

#define NBLK 2048
#define WPB 4                            // waves per block
#define TOT_WAVES (NBLK * WPB)           // 8192
#define ROWS_PER_WAVE (NROWS / TOT_WAVES) // 16

typedef float vf4 __attribute__((ext_vector_type(4)));

__device__ __forceinline__ float4 ld4(const float* p) { return *(const float4*)p; }

// d_ws layout: float part_sum[NBLK]; float part_max[NBLK]
__global__ __launch_bounds__(256) void stencil7_kernel(
    const float* __restrict__ x, const float* __restrict__ coeff,
    const float* __restrict__ ref, float* __restrict__ outD,   // = d_out base (16B aligned)
    float* __restrict__ part_sum, float* __restrict__ part_max)
{
    const int tid  = threadIdx.x;
    const int wave = tid >> 6;
    const int lane = tid & 63;
    const int waveId = blockIdx.x * WPB + wave;
    const int z0   = lane << 2;

    float acc_s = 0.f;
    float acc_m = 0.f;

    #pragma unroll 1
    for (int it = 0; it < ROWS_PER_WAVE; ++it) {
        const int r = waveId + it * TOT_WAVES;   // row index
        const int w = r & (WW - 1);
        const int h = (r >> 8) & (HH - 1);
        const long long base = (long long)r * ZZ;

        const float4 cen = ld4(x + base + z0);
        float4 west  = make_float4(0.f, 0.f, 0.f, 0.f);
        float4 east  = west, south = west, north = west;
        if (w > 0)      west  = ld4(x + base - ZZ + z0);
        if (w < WW - 1) east  = ld4(x + base + ZZ + z0);
        if (h > 0)      south = ld4(x + base - (long long)WW * ZZ + z0);
        if (h < HH - 1) north = ld4(x + base + (long long)WW * ZZ + z0);
        const float4 rf = ld4(ref + base + z0);

        // coeff via scalar path (wave-uniform address -> s_load, no VMEM)
        const float* cp = coeff + 7LL * __builtin_amdgcn_readfirstlane(r);
        const float c0 = cp[0], c1 = cp[1], c2 = cp[2], c3 = cp[3];
        const float c4 = cp[4], c5 = cp[5], c6 = cp[6];

        // Z-direction shifts via cross-lane shuffle (wave = one full Z-row)
        float bm1 = __shfl_up(cen.w, 1);
        if (lane == 0) bm1 = 0.f;
        float tp1 = __shfl_down(cen.x, 1);
        if (lane == 63) tp1 = 0.f;

        const float4 bot = make_float4(bm1, cen.x, cen.y, cen.z);
        const float4 top = make_float4(cen.y, cen.z, cen.w, tp1);

        float4 o;
        o.x = c0*west.x + c1*east.x + c2*south.x + c3*north.x + c4*bot.x + c5*top.x + c6*cen.x;
        o.y = c0*west.y + c1*east.y + c2*south.y + c3*north.y + c4*bot.y + c5*top.y + c6*cen.y;
        o.z = c0*west.z + c1*east.z + c2*south.z + c3*north.z + c4*bot.z + c5*top.z + c6*cen.z;
        o.w = c0*west.w + c1*east.w + c2*south.w + c3*north.w + c4*bot.w + c5*top.w + c6*cen.w;

        // ---- aligned store of the 4B-offset output ----
        // d_out element for z is outD[base + z + 1]. Aligned float4 slot k
        // (k=1..63) covers z = {4k-1,4k,4k+1,4k+2}; lane j stores slot j+1 =
        // {own o.w, next-lane o.x, o.y, o.z}. Edges: z=0,1,2 (lane 0) and
        // z=255 (lane 63) as scalar dwords. Rows never overlap.
        const float nx = __shfl_down(o.x, 1);
        const float ny = __shfl_down(o.y, 1);
        const float nz = __shfl_down(o.z, 1);
        float* rowp = outD + base;               // 1024B-aligned
        if (lane < 63) {
            vf4 st; st.x = o.w; st.y = nx; st.z = ny; st.w = nz;
            __builtin_nontemporal_store(st, (vf4*)(rowp + 4 * (lane + 1)));
        }
        if (lane == 0) { rowp[1] = o.x; rowp[2] = o.y; rowp[3] = o.z; }
        if (lane == 63) rowp[ZZ] = o.w;

        // error reductions
        const float ex = o.x - rf.x, ey = o.y - rf.y, ez = o.z - rf.z, ew = o.w - rf.w;
        acc_s += ex*ex + ey*ey + ez*ez + ew*ew;
        acc_m  = fmaxf(acc_m, fmaxf(fmaxf(fabsf(ex), fabsf(ey)),
                                    fmaxf(fabsf(ez), fabsf(ew))));
    }

    // wave reduction
    #pragma unroll
    for (int off = 32; off > 0; off >>= 1) {
        acc_s += __shfl_down(acc_s, off);
        acc_m  = fmaxf(acc_m, __shfl_down(acc_m, off));
    }

    __shared__ float ss[WPB];
    __shared__ float sm[WPB];
    if (lane == 0) { ss[wave] = acc_s; sm[wave] = acc_m; }
    __syncthreads();
    if (tid == 0) {
        part_sum[blockIdx.x] = ss[0] + ss[1] + ss[2] + ss[3];
        part_max[blockIdx.x] = fmaxf(fmaxf(sm[0], sm[1]), fmaxf(sm[2], sm[3]));
    }
}

__global__ __launch_bounds__(256) void finalize_kernel(
    const float* __restrict__ part_sum, const float* __restrict__ part_max,
    float* __restrict__ loss_out, float* __restrict__ amax_out)
{
    const int tid  = threadIdx.x;
    const int wave = tid >> 6;
    const int lane = tid & 63;

    double s = 0.0;
    float  m = 0.f;
    for (int i = tid; i < NBLK; i += 256) {
        s += (double)part_sum[i];
        m  = fmaxf(m, part_max[i]);
    }
    #pragma unroll
    for (int off = 32; off > 0; off >>= 1) {
        s += __shfl_down(s, off);
        m  = fmaxf(m, __shfl_down(m, off));
    }
    __shared__ double ds[4];
    __shared__ float  dm[4];
    if (lane == 0) { ds[wave] = s; dm[wave] = m; }
    __syncthreads();
    if (tid == 0) {
        const double S = ds[0] + ds[1] + ds[2] + ds[3];
        const float  M = fmaxf(fmaxf(dm[0], dm[1]), fmaxf(dm[2], dm[3]));
        *loss_out = (float)(S / (double)NELEM);
        *amax_out = M;
    }
}

extern "C" void kernel_launch(void* const* d_in, const int* in_sizes, int n_in,
                              void* d_out, int out_size, void* d_ws, size_t ws_size,
                              hipStream_t stream) {
    const float* x     = (const float*)d_in[0];
    const float* coeff = (const float*)d_in[1];
    const float* ref   = (const float*)d_in[2];

    float* outf = (float*)d_out;
    float* loss_out = outf;               // d_out[0]
    float* amax_out = outf + 1 + NELEM;   // d_out[N+1]

    float* part_sum = (float*)d_ws;
    float* part_max = part_sum + NBLK;

    stencil7_kernel<<<dim3(NBLK), dim3(256), 0, stream>>>(
        x, coeff, ref, outf, part_sum, part_max);
    finalize_kernel<<<dim3(1), dim3(256), 0, stream>>>(
        part_sum, part_max, loss_out, amax_out);
}